// Round 6
// baseline (323.175 us; speedup 1.0000x reference)
//
#include <hip/hip_runtime.h>
#include <cstdint>
#include <cstddef>

// GATv2 x2. Round 6: back to 1-edge-per-wave (R4 layout) + depth-4 gather
// pipeline + exp2-domain softmax. GEMM/CSR/casts unchanged.
// N=50000, E=800000, H=2, C_IN=256, C1=64, C2=128.

#define NEG_SLOPE 0.2f

typedef _Float16 f16x8 __attribute__((ext_vector_type(8)));
typedef _Float16 f16x4 __attribute__((ext_vector_type(4)));
typedef _Float16 f16x2 __attribute__((ext_vector_type(2)));
typedef float f32x4 __attribute__((ext_vector_type(4)));

#if __has_builtin(__builtin_amdgcn_exp2f)
#define EXP2(x) __builtin_amdgcn_exp2f(x)
#else
#define EXP2(x) __expf((x)*0.69314718056f)
#endif

// x += dpp_perm(x). 0xB1=quad xor1, 0x4E=quad xor2, 0x124=row_ror:4, 0x128=row_ror:8
#define DPPADD(x, CTRL)                                                        \
  do {                                                                         \
    int _y = __builtin_amdgcn_update_dpp(0, __float_as_int(x), CTRL, 0xf, 0xf, \
                                         true);                                \
    x += __int_as_float(_y);                                                   \
  } while (0)

// ---------------------------------------------------------------------------
__global__ __launch_bounds__(256) void cast_f2h(
    const float* __restrict__ src, _Float16* __restrict__ dst, int total4) {
  const int t = blockIdx.x * blockDim.x + threadIdx.x;
  if (t >= total4) return;
  const float4 v = *(const float4*)&src[(size_t)t * 4];
  f16x4 h;
  h[0] = (_Float16)v.x; h[1] = (_Float16)v.y; h[2] = (_Float16)v.z; h[3] = (_Float16)v.w;
  *(f16x4*)&dst[(size_t)t * 4] = h;
}

__global__ __launch_bounds__(256) void tcast_w(
    const float* __restrict__ Wl, const float* __restrict__ Wr,
    _Float16* __restrict__ Bt, int K, int NH) {
  const int t = blockIdx.x * blockDim.x + threadIdx.x;
  if (t >= 2 * NH * K) return;
  const int n = t / K, k = t - n * K;
  const float v = (n < NH) ? Wl[(size_t)k * NH + n] : Wr[(size_t)k * NH + (n - NH)];
  Bt[t] = (_Float16)v;
}

// ---------------------------------------------------------------------------
// C[M][NT](f16) = A[M][K](f16) @ Bt[NT][K]^T. 128x64 tile, BK=64, 4 waves.
__global__ __launch_bounds__(256) void hgemm_tn(
    const _Float16* __restrict__ A, const _Float16* __restrict__ Bt,
    _Float16* __restrict__ C, int M, int NT, int K) {
  constexpr int LDA = 88;
  __shared__ _Float16 As[128 * LDA];
  __shared__ _Float16 Bs[64 * LDA];
  const int bm = blockIdx.y * 128;
  const int bn = blockIdx.x * 64;
  const int tid = threadIdx.x;
  const int lane = tid & 63;
  const int wave = tid >> 6;
  const int wr = (wave >> 1) * 64;
  const int wc = (wave & 1) * 32;
  const int l15 = lane & 15;
  const int kq = (lane >> 4) * 8;
  f32x4 acc[4][2] = {};
  for (int k0 = 0; k0 < K; k0 += 64) {
    f16x8 a[4], b[2];
#pragma unroll
    for (int i = 0; i < 4; ++i) {
      const int c = tid + 256 * i;
      const int r = c >> 3, ks = (c & 7) * 8;
      const int row = bm + r;
      a[i] = (row < M) ? *(const f16x8*)&A[(size_t)row * K + k0 + ks] : f16x8{};
    }
#pragma unroll
    for (int i = 0; i < 2; ++i) {
      const int c = tid + 256 * i;
      const int r = c >> 3, ks = (c & 7) * 8;
      b[i] = *(const f16x8*)&Bt[(size_t)(bn + r) * K + k0 + ks];
    }
    __syncthreads();
#pragma unroll
    for (int i = 0; i < 4; ++i) {
      const int c = tid + 256 * i;
      const int r = c >> 3, ks = (c & 7) * 8;
      *(f16x8*)&As[r * LDA + ks] = a[i];
    }
#pragma unroll
    for (int i = 0; i < 2; ++i) {
      const int c = tid + 256 * i;
      const int r = c >> 3, ks = (c & 7) * 8;
      *(f16x8*)&Bs[r * LDA + ks] = b[i];
    }
    __syncthreads();
#pragma unroll
    for (int kk = 0; kk < 64; kk += 32) {
      f16x8 bf[2];
#pragma unroll
      for (int ni = 0; ni < 2; ++ni)
        bf[ni] = *(const f16x8*)&Bs[(wc + ni * 16 + l15) * LDA + kk + kq];
#pragma unroll
      for (int mi = 0; mi < 4; ++mi) {
        const f16x8 af = *(const f16x8*)&As[(wr + mi * 16 + l15) * LDA + kk + kq];
#pragma unroll
        for (int ni = 0; ni < 2; ++ni)
          acc[mi][ni] = __builtin_amdgcn_mfma_f32_16x16x32_f16(af, bf[ni], acc[mi][ni], 0, 0, 0);
      }
    }
  }
  const int crow0 = (lane >> 4) * 4;
#pragma unroll
  for (int mi = 0; mi < 4; ++mi) {
#pragma unroll
    for (int r = 0; r < 4; ++r) {
      const int row = bm + wr + mi * 16 + crow0 + r;
      if (row < M) {
#pragma unroll
        for (int ni = 0; ni < 2; ++ni)
          C[(size_t)row * NT + bn + wc + ni * 16 + l15] = (_Float16)acc[mi][ni][r];
      }
    }
  }
}

// ---------------------------------------------------------------------------
// CSR build (self-loops appended as (n->n)).
__global__ __launch_bounds__(256) void csr_count(
    const int* __restrict__ ei, int E, int EA, int* __restrict__ cnt) {
  const int i = blockIdx.x * blockDim.x + threadIdx.x;
  if (i >= EA) return;
  const int dst = (i < E) ? ei[E + i] : (i - E);
  atomicAdd(&cnt[dst], 1);
}

__global__ __launch_bounds__(256) void scan_block(
    const int* __restrict__ cnt, int* __restrict__ excl,
    int* __restrict__ bsum, int n) {
  __shared__ int s[256];
  const int tid = threadIdx.x;
  const int i = blockIdx.x * 256 + tid;
  const int v = (i < n) ? cnt[i] : 0;
  s[tid] = v;
  __syncthreads();
  for (int off = 1; off < 256; off <<= 1) {
    const int t = (tid >= off) ? s[tid - off] : 0;
    __syncthreads();
    s[tid] += t;
    __syncthreads();
  }
  if (i < n) excl[i] = s[tid] - v;
  if (tid == 255) bsum[blockIdx.x] = s[255];
}

__global__ __launch_bounds__(256) void scan_top(
    const int* __restrict__ bsum, int* __restrict__ bofs, int nb) {
  __shared__ int s[256];
  const int tid = threadIdx.x;
  const int v = (tid < nb) ? bsum[tid] : 0;
  s[tid] = v;
  __syncthreads();
  for (int off = 1; off < 256; off <<= 1) {
    const int t = (tid >= off) ? s[tid - off] : 0;
    __syncthreads();
    s[tid] += t;
    __syncthreads();
  }
  if (tid < nb) bofs[tid] = s[tid] - v;
}

__global__ __launch_bounds__(256) void scan_add(
    int* __restrict__ rowptr, const int* __restrict__ bofs, int n, int EA) {
  const int i = blockIdx.x * blockDim.x + threadIdx.x;
  if (i < n) rowptr[i] += bofs[i >> 8];
  if (i == 0) rowptr[n] = EA;
}

__global__ __launch_bounds__(256) void csr_fill(
    const int* __restrict__ ei, int E, int EA,
    const int* __restrict__ rowptr, int* __restrict__ wo,
    int* __restrict__ col) {
  const int i = blockIdx.x * blockDim.x + threadIdx.x;
  if (i >= EA) return;
  int src, dst;
  if (i < E) { src = ei[i]; dst = ei[E + i]; } else { src = dst = i - E; }
  const int pos = atomicAdd(&wo[dst], 1);
  col[rowptr[dst] + pos] = src;
}

// ---------------------------------------------------------------------------
// Fused per-node GATv2, 1 edge/wave, depth-4 gather pipeline, exp2 softmax.
// Lanes 0-31 head0, 32-63 head1; V = C/32 ch/lane; att pre-scaled by log2(e).
template <int C, int LOGS, int V, bool RELU, bool OUT16>
__global__ __launch_bounds__(256) void fused_gat_h(
    const int* __restrict__ rowptr, const int* __restrict__ col,
    const _Float16* __restrict__ feat, const float* __restrict__ att,
    const float* __restrict__ bias, _Float16* __restrict__ out16,
    float* __restrict__ out32, int N) {
  constexpr int P = V / 2;
  constexpr int D = 4;  // pipeline depth
  typedef _Float16 hv __attribute__((ext_vector_type(V)));
  const int n = blockIdx.x * 4 + (threadIdx.x >> 6);
  if (n >= N) return;
  const int lane = threadIdx.x & 63;
  const int h = lane >> 5;
  const int co = h * C + (lane & 31) * V;

  f16x2 xr2[P], at2[P];
  float O[V];
  {
    const int base = (n << LOGS) + 2 * C + co;
#pragma unroll
    for (int p = 0; p < P; ++p) xr2[p] = *(const f16x2*)&feat[base + 2 * p];
#pragma unroll
    for (int p = 0; p < P; ++p)
      at2[p] = f16x2{(_Float16)(att[co + 2 * p] * 1.44269504f),
                     (_Float16)(att[co + 2 * p + 1] * 1.44269504f)};
#pragma unroll
    for (int j = 0; j < V; ++j) O[j] = 0.f;
  }
  float m = -1e30f, l = 0.f;
  const int e0 = rowptr[n], e1 = rowptr[n + 1];
  const int e1m1 = e1 - 1;

  hv f[D];
#pragma unroll
  for (int k = 0; k < D; ++k) {
    const int ek = e0 + k;
    const int ck = col[(ek < e1) ? ek : e1m1];
    f[k] = *(const hv*)&feat[(ck << LOGS) + co];
  }

  for (int base = e0; base < e1; base += D) {
#pragma unroll
    for (int k = 0; k < D; ++k) {
      const bool valid = (base + k) < e1;
      const int en = base + k + D;
      const int cn = col[(en < e1) ? en : e1m1];
      // logit (log2 domain: att pre-scaled)
      float pacc = 0.f;
#pragma unroll
      for (int p = 0; p < P; ++p) {
        const f16x2 c2 = f16x2{f[k][2 * p], f[k][2 * p + 1]};
        const f16x2 s = c2 + xr2[p];
        const f16x2 mx = __builtin_elementwise_max(s, f16x2{(_Float16)0.f, (_Float16)0.f});
        const f16x2 mn = __builtin_elementwise_min(s, f16x2{(_Float16)0.f, (_Float16)0.f});
        const f16x2 lk = mn * f16x2{(_Float16)NEG_SLOPE, (_Float16)NEG_SLOPE} + mx;
        pacc = __builtin_amdgcn_fdot2(lk, at2[p], pacc, false);
      }
      // reduce over my 32-lane head half
      DPPADD(pacc, 0xB1);
      DPPADD(pacc, 0x4E);
      DPPADD(pacc, 0x124);
      DPPADD(pacc, 0x128);
      pacc += __shfl_xor(pacc, 16, 64);
      if (!valid) pacc = -INFINITY;
      // online softmax, defer-max (11.54 log2-units ~= e^8)
      if (__any(pacc - m > 11.54f)) {
        const float mn2 = fmaxf(m, pacc);
        const float scale = EXP2(m - mn2);
        const float w = valid ? EXP2(pacc - mn2) : 0.f;
        l = l * scale + w;
#pragma unroll
        for (int j = 0; j < V; ++j) O[j] = O[j] * scale + w * (float)f[k][j];
        m = mn2;
      } else {
        const float w = EXP2(pacc - m);
        l += w;
#pragma unroll
        for (int j = 0; j < V; ++j) O[j] += w * (float)f[k][j];
      }
      // refill pipeline slot (wave-uniform guard avoids tail over-fetch)
      if (en < e1) f[k] = *(const hv*)&feat[(cn << LOGS) + co];
    }
  }

  const float inv = 1.f / l;
  if constexpr (OUT16) {
    typedef _Float16 ov __attribute__((ext_vector_type(V)));
    ov o;
#pragma unroll
    for (int j = 0; j < V; ++j) {
      float v = O[j] * inv + bias[co + j];
      if constexpr (RELU) v = fmaxf(v, 0.f);
      o[j] = (_Float16)v;
    }
    *(ov*)&out16[n * (2 * C) + co] = o;
  } else {
    float4 o;
    o.x = O[0] * inv + bias[co + 0];
    o.y = O[1] * inv + bias[co + 1];
    o.z = O[2] * inv + bias[co + 2];
    o.w = O[3] * inv + bias[co + 3];
    *(float4*)&out32[(size_t)n * (2 * C) + co] = o;
  }
}

// ---------------------------------------------------------------------------
extern "C" void kernel_launch(void* const* d_in, const int* in_sizes, int n_in,
                              void* d_out, int out_size, void* d_ws, size_t ws_size,
                              hipStream_t stream) {
  const float* x    = (const float*)d_in[0];
  const int*   ei   = (const int*)d_in[1];
  const float* Wl0  = (const float*)d_in[2];
  const float* Wr0  = (const float*)d_in[3];
  const float* att0 = (const float*)d_in[4];
  const float* b0   = (const float*)d_in[5];
  const float* Wl1  = (const float*)d_in[6];
  const float* Wr1  = (const float*)d_in[7];
  const float* att1 = (const float*)d_in[8];
  const float* b1   = (const float*)d_in[9];
  float* out = (float*)d_out;

  const int N  = in_sizes[0] / 256;
  const int E  = in_sizes[1] / 2;
  const int EA = E + N;

  _Float16* hw    = (_Float16*)d_ws;
  _Float16* feat0 = hw;                        // N x 256 (overlapped by feat1)
  _Float16* feat1 = hw;                        // N x 512
  _Float16* ha    = hw + (size_t)N * 512;      // N x 128 (L0 out, f16)
  _Float16* xa    = hw + (size_t)N * 640;      // N x 256 (x in f16)
  _Float16* Bt0   = hw + (size_t)N * 896;      // 256 x 256
  _Float16* Bt1   = Bt0 + 65536;               // 512 x 128
  int* rowptr = (int*)(Bt1 + 65536);
  int* cnt    = rowptr + (N + 1);
  int* wo     = cnt + N;
  int* bsum   = wo + N;
  int* bofs   = bsum + 256;
  int* col    = bofs + 256;

  const dim3 blk(256);
  const int gEA   = (EA + 255) / 256;
  const int gScan = (N + 255) / 256;
  const int gM    = (N + 127) / 128;
  const int gNode = (N + 3) / 4;

  cast_f2h<<<(N * 64 + 255) / 256, blk, 0, stream>>>(x, xa, N * 64);
  tcast_w<<<(65536 + 255) / 256, blk, 0, stream>>>(Wl0, Wr0, Bt0, 256, 128);
  tcast_w<<<(65536 + 255) / 256, blk, 0, stream>>>(Wl1, Wr1, Bt1, 128, 256);

  hipMemsetAsync(cnt, 0, (size_t)N * 4, stream);
  hipMemsetAsync(wo, 0, (size_t)N * 4, stream);
  csr_count<<<gEA, blk, 0, stream>>>(ei, E, EA, cnt);
  scan_block<<<gScan, blk, 0, stream>>>(cnt, rowptr, bsum, N);
  scan_top<<<1, blk, 0, stream>>>(bsum, bofs, gScan);
  scan_add<<<gScan, blk, 0, stream>>>(rowptr, bofs, N, EA);
  csr_fill<<<gEA, blk, 0, stream>>>(ei, E, EA, rowptr, wo, col);

  // Layer 0  (C=64, stride 256 halves -> LOGS=8, V=2)
  hgemm_tn<<<dim3(4, gM), blk, 0, stream>>>(xa, Bt0, feat0, N, 256, 256);
  fused_gat_h<64, 8, 2, true, true><<<gNode, blk, 0, stream>>>(
      rowptr, col, feat0, att0, b0, ha, nullptr, N);

  // Layer 1  (C=128, stride 512 halves -> LOGS=9, V=4)
  hgemm_tn<<<dim3(8, gM), blk, 0, stream>>>(ha, Bt1, feat1, N, 512, 128);
  fused_gat_h<128, 9, 4, false, false><<<gNode, blk, 0, stream>>>(
      rowptr, col, feat1, att1, b1, nullptr, out, N);
}

// Round 7
// 291.387 us; speedup vs baseline: 1.1091x; 1.1091x over previous
//
#include <hip/hip_runtime.h>
#include <cstdint>
#include <cstddef>

// GATv2 x2. Round 7: UNCONDITIONAL clamped-index refills (statically countable
// vmcnt -> real depth-6 gather pipeline), col prefetched one unroll ahead.
// GEMM/CSR/casts unchanged. N=50000, E=800000, H=2, C_IN=256, C1=64, C2=128.

#define NEG_SLOPE 0.2f

typedef _Float16 f16x8 __attribute__((ext_vector_type(8)));
typedef _Float16 f16x4 __attribute__((ext_vector_type(4)));
typedef _Float16 f16x2 __attribute__((ext_vector_type(2)));
typedef float f32x4 __attribute__((ext_vector_type(4)));

#if __has_builtin(__builtin_amdgcn_exp2f)
#define EXP2(x) __builtin_amdgcn_exp2f(x)
#else
#define EXP2(x) __expf((x)*0.69314718056f)
#endif

// x += dpp_perm(x). 0xB1=quad xor1, 0x4E=quad xor2, 0x124=row_ror:4, 0x128=row_ror:8
#define DPPADD(x, CTRL)                                                        \
  do {                                                                         \
    int _y = __builtin_amdgcn_update_dpp(0, __float_as_int(x), CTRL, 0xf, 0xf, \
                                         true);                                \
    x += __int_as_float(_y);                                                   \
  } while (0)

// ---------------------------------------------------------------------------
__global__ __launch_bounds__(256) void cast_f2h(
    const float* __restrict__ src, _Float16* __restrict__ dst, int total4) {
  const int t = blockIdx.x * blockDim.x + threadIdx.x;
  if (t >= total4) return;
  const float4 v = *(const float4*)&src[(size_t)t * 4];
  f16x4 h;
  h[0] = (_Float16)v.x; h[1] = (_Float16)v.y; h[2] = (_Float16)v.z; h[3] = (_Float16)v.w;
  *(f16x4*)&dst[(size_t)t * 4] = h;
}

__global__ __launch_bounds__(256) void tcast_w(
    const float* __restrict__ Wl, const float* __restrict__ Wr,
    _Float16* __restrict__ Bt, int K, int NH) {
  const int t = blockIdx.x * blockDim.x + threadIdx.x;
  if (t >= 2 * NH * K) return;
  const int n = t / K, k = t - n * K;
  const float v = (n < NH) ? Wl[(size_t)k * NH + n] : Wr[(size_t)k * NH + (n - NH)];
  Bt[t] = (_Float16)v;
}

// ---------------------------------------------------------------------------
// C[M][NT](f16) = A[M][K](f16) @ Bt[NT][K]^T. 128x64 tile, BK=64, 4 waves.
__global__ __launch_bounds__(256) void hgemm_tn(
    const _Float16* __restrict__ A, const _Float16* __restrict__ Bt,
    _Float16* __restrict__ C, int M, int NT, int K) {
  constexpr int LDA = 88;
  __shared__ _Float16 As[128 * LDA];
  __shared__ _Float16 Bs[64 * LDA];
  const int bm = blockIdx.y * 128;
  const int bn = blockIdx.x * 64;
  const int tid = threadIdx.x;
  const int lane = tid & 63;
  const int wave = tid >> 6;
  const int wr = (wave >> 1) * 64;
  const int wc = (wave & 1) * 32;
  const int l15 = lane & 15;
  const int kq = (lane >> 4) * 8;
  f32x4 acc[4][2] = {};
  for (int k0 = 0; k0 < K; k0 += 64) {
    f16x8 a[4], b[2];
#pragma unroll
    for (int i = 0; i < 4; ++i) {
      const int c = tid + 256 * i;
      const int r = c >> 3, ks = (c & 7) * 8;
      const int row = bm + r;
      a[i] = (row < M) ? *(const f16x8*)&A[(size_t)row * K + k0 + ks] : f16x8{};
    }
#pragma unroll
    for (int i = 0; i < 2; ++i) {
      const int c = tid + 256 * i;
      const int r = c >> 3, ks = (c & 7) * 8;
      b[i] = *(const f16x8*)&Bt[(size_t)(bn + r) * K + k0 + ks];
    }
    __syncthreads();
#pragma unroll
    for (int i = 0; i < 4; ++i) {
      const int c = tid + 256 * i;
      const int r = c >> 3, ks = (c & 7) * 8;
      *(f16x8*)&As[r * LDA + ks] = a[i];
    }
#pragma unroll
    for (int i = 0; i < 2; ++i) {
      const int c = tid + 256 * i;
      const int r = c >> 3, ks = (c & 7) * 8;
      *(f16x8*)&Bs[r * LDA + ks] = b[i];
    }
    __syncthreads();
#pragma unroll
    for (int kk = 0; kk < 64; kk += 32) {
      f16x8 bf[2];
#pragma unroll
      for (int ni = 0; ni < 2; ++ni)
        bf[ni] = *(const f16x8*)&Bs[(wc + ni * 16 + l15) * LDA + kk + kq];
#pragma unroll
      for (int mi = 0; mi < 4; ++mi) {
        const f16x8 af = *(const f16x8*)&As[(wr + mi * 16 + l15) * LDA + kk + kq];
#pragma unroll
        for (int ni = 0; ni < 2; ++ni)
          acc[mi][ni] = __builtin_amdgcn_mfma_f32_16x16x32_f16(af, bf[ni], acc[mi][ni], 0, 0, 0);
      }
    }
  }
  const int crow0 = (lane >> 4) * 4;
#pragma unroll
  for (int mi = 0; mi < 4; ++mi) {
#pragma unroll
    for (int r = 0; r < 4; ++r) {
      const int row = bm + wr + mi * 16 + crow0 + r;
      if (row < M) {
#pragma unroll
        for (int ni = 0; ni < 2; ++ni)
          C[(size_t)row * NT + bn + wc + ni * 16 + l15] = (_Float16)acc[mi][ni][r];
      }
    }
  }
}

// ---------------------------------------------------------------------------
// CSR build (self-loops appended as (n->n)).
__global__ __launch_bounds__(256) void csr_count(
    const int* __restrict__ ei, int E, int EA, int* __restrict__ cnt) {
  const int i = blockIdx.x * blockDim.x + threadIdx.x;
  if (i >= EA) return;
  const int dst = (i < E) ? ei[E + i] : (i - E);
  atomicAdd(&cnt[dst], 1);
}

__global__ __launch_bounds__(256) void scan_block(
    const int* __restrict__ cnt, int* __restrict__ excl,
    int* __restrict__ bsum, int n) {
  __shared__ int s[256];
  const int tid = threadIdx.x;
  const int i = blockIdx.x * 256 + tid;
  const int v = (i < n) ? cnt[i] : 0;
  s[tid] = v;
  __syncthreads();
  for (int off = 1; off < 256; off <<= 1) {
    const int t = (tid >= off) ? s[tid - off] : 0;
    __syncthreads();
    s[tid] += t;
    __syncthreads();
  }
  if (i < n) excl[i] = s[tid] - v;
  if (tid == 255) bsum[blockIdx.x] = s[255];
}

__global__ __launch_bounds__(256) void scan_top(
    const int* __restrict__ bsum, int* __restrict__ bofs, int nb) {
  __shared__ int s[256];
  const int tid = threadIdx.x;
  const int v = (tid < nb) ? bsum[tid] : 0;
  s[tid] = v;
  __syncthreads();
  for (int off = 1; off < 256; off <<= 1) {
    const int t = (tid >= off) ? s[tid - off] : 0;
    __syncthreads();
    s[tid] += t;
    __syncthreads();
  }
  if (tid < nb) bofs[tid] = s[tid] - v;
}

__global__ __launch_bounds__(256) void scan_add(
    int* __restrict__ rowptr, const int* __restrict__ bofs, int n, int EA) {
  const int i = blockIdx.x * blockDim.x + threadIdx.x;
  if (i < n) rowptr[i] += bofs[i >> 8];
  if (i == 0) rowptr[n] = EA;
}

__global__ __launch_bounds__(256) void csr_fill(
    const int* __restrict__ ei, int E, int EA,
    const int* __restrict__ rowptr, int* __restrict__ wo,
    int* __restrict__ col) {
  const int i = blockIdx.x * blockDim.x + threadIdx.x;
  if (i >= EA) return;
  int src, dst;
  if (i < E) { src = ei[i]; dst = ei[E + i]; } else { src = dst = i - E; }
  const int pos = atomicAdd(&wo[dst], 1);
  col[rowptr[dst] + pos] = src;
}

// ---------------------------------------------------------------------------
// Fused per-node GATv2, 1 edge/wave, depth-D pipeline with UNCONDITIONAL
// clamped-index loads (statically countable vmcnt). exp2-domain softmax.
// Lanes 0-31 head0, 32-63 head1; V = C/32 ch/lane; att pre-scaled by log2(e).
template <int C, int LOGS, int V, int D, bool RELU, bool OUT16>
__global__ __launch_bounds__(256) void fused_gat_h(
    const int* __restrict__ rowptr, const int* __restrict__ col,
    const _Float16* __restrict__ feat, const float* __restrict__ att,
    const float* __restrict__ bias, _Float16* __restrict__ out16,
    float* __restrict__ out32, int N) {
  constexpr int P = V / 2;
  typedef _Float16 hv __attribute__((ext_vector_type(V)));
  const int n = blockIdx.x * 4 + (threadIdx.x >> 6);
  if (n >= N) return;
  const int lane = threadIdx.x & 63;
  const int h = lane >> 5;
  const int co = h * C + (lane & 31) * V;

  f16x2 xr2[P], at2[P];
  float O[V];
  {
    const int base = (n << LOGS) + 2 * C + co;
#pragma unroll
    for (int p = 0; p < P; ++p) xr2[p] = *(const f16x2*)&feat[base + 2 * p];
#pragma unroll
    for (int p = 0; p < P; ++p)
      at2[p] = f16x2{(_Float16)(att[co + 2 * p] * 1.44269504f),
                     (_Float16)(att[co + 2 * p + 1] * 1.44269504f)};
#pragma unroll
    for (int j = 0; j < V; ++j) O[j] = 0.f;
  }
  float m = -1e30f, l = 0.f;
  const int e0 = rowptr[n], e1 = rowptr[n + 1];
  const int e1m1 = e1 - 1;

  // pipeline: f[k] holds feat row for edge (base+k); cidx[k] holds col for
  // edge (base+D+k). All loads unconditional; indices clamped to e1m1.
  hv f[D];
  int cidx[D];
#pragma unroll
  for (int k = 0; k < D; ++k) {
    const int ek = e0 + k;
    const int ck = col[(ek < e1) ? ek : e1m1];
    f[k] = *(const hv*)&feat[(ck << LOGS) + co];
  }
#pragma unroll
  for (int k = 0; k < D; ++k) {
    const int ek = e0 + D + k;
    cidx[k] = col[(ek < e1) ? ek : e1m1];
  }

  for (int basee = e0; basee < e1; basee += D) {
#pragma unroll
    for (int k = 0; k < D; ++k) {
      const int eid = basee + k;
      const bool valid = eid < e1;
      // logit (log2 domain: att pre-scaled)
      float pacc = 0.f;
#pragma unroll
      for (int p = 0; p < P; ++p) {
        const f16x2 c2 = f16x2{f[k][2 * p], f[k][2 * p + 1]};
        const f16x2 s = c2 + xr2[p];
        const f16x2 mx = __builtin_elementwise_max(s, f16x2{(_Float16)0.f, (_Float16)0.f});
        const f16x2 mn = __builtin_elementwise_min(s, f16x2{(_Float16)0.f, (_Float16)0.f});
        const f16x2 lk = mn * f16x2{(_Float16)NEG_SLOPE, (_Float16)NEG_SLOPE} + mx;
        pacc = __builtin_amdgcn_fdot2(lk, at2[p], pacc, false);
      }
      // reduce over my 32-lane head half
      DPPADD(pacc, 0xB1);
      DPPADD(pacc, 0x4E);
      DPPADD(pacc, 0x124);
      DPPADD(pacc, 0x128);
      pacc += __shfl_xor(pacc, 16, 64);
      if (!valid) pacc = -INFINITY;
      // online softmax, defer-max (11.54 log2-units ~= e^8)
      if (__any(pacc - m > 11.54f)) {
        const float mn2 = fmaxf(m, pacc);
        const float scale = EXP2(m - mn2);
        const float w = valid ? EXP2(pacc - mn2) : 0.f;
        l = l * scale + w;
#pragma unroll
        for (int j = 0; j < V; ++j) O[j] = O[j] * scale + w * (float)f[k][j];
        m = mn2;
      } else {
        const float w = EXP2(pacc - m);  // EXP2(-inf)=0 masks invalids
        l += w;
#pragma unroll
        for (int j = 0; j < V; ++j) O[j] += w * (float)f[k][j];
      }
      // UNCONDITIONAL refill (clamped index) -> countable vmcnt, depth-D MLP
      f[k] = *(const hv*)&feat[(cidx[k] << LOGS) + co];
      const int enn = eid + 2 * D;
      cidx[k] = col[(enn < e1) ? enn : e1m1];
    }
  }

  const float inv = 1.f / l;
  if constexpr (OUT16) {
    typedef _Float16 ov __attribute__((ext_vector_type(V)));
    ov o;
#pragma unroll
    for (int j = 0; j < V; ++j) {
      float v = O[j] * inv + bias[co + j];
      if constexpr (RELU) v = fmaxf(v, 0.f);
      o[j] = (_Float16)v;
    }
    *(ov*)&out16[n * (2 * C) + co] = o;
  } else {
    float4 o;
    o.x = O[0] * inv + bias[co + 0];
    o.y = O[1] * inv + bias[co + 1];
    o.z = O[2] * inv + bias[co + 2];
    o.w = O[3] * inv + bias[co + 3];
    *(float4*)&out32[(size_t)n * (2 * C) + co] = o;
  }
}

// ---------------------------------------------------------------------------
extern "C" void kernel_launch(void* const* d_in, const int* in_sizes, int n_in,
                              void* d_out, int out_size, void* d_ws, size_t ws_size,
                              hipStream_t stream) {
  const float* x    = (const float*)d_in[0];
  const int*   ei   = (const int*)d_in[1];
  const float* Wl0  = (const float*)d_in[2];
  const float* Wr0  = (const float*)d_in[3];
  const float* att0 = (const float*)d_in[4];
  const float* b0   = (const float*)d_in[5];
  const float* Wl1  = (const float*)d_in[6];
  const float* Wr1  = (const float*)d_in[7];
  const float* att1 = (const float*)d_in[8];
  const float* b1   = (const float*)d_in[9];
  float* out = (float*)d_out;

  const int N  = in_sizes[0] / 256;
  const int E  = in_sizes[1] / 2;
  const int EA = E + N;

  _Float16* hw    = (_Float16*)d_ws;
  _Float16* feat0 = hw;                        // N x 256 (overlapped by feat1)
  _Float16* feat1 = hw;                        // N x 512
  _Float16* ha    = hw + (size_t)N * 512;      // N x 128 (L0 out, f16)
  _Float16* xa    = hw + (size_t)N * 640;      // N x 256 (x in f16)
  _Float16* Bt0   = hw + (size_t)N * 896;      // 256 x 256
  _Float16* Bt1   = Bt0 + 65536;               // 512 x 128
  int* rowptr = (int*)(Bt1 + 65536);
  int* cnt    = rowptr + (N + 1);
  int* wo     = cnt + N;
  int* bsum   = wo + N;
  int* bofs   = bsum + 256;
  int* col    = bofs + 256;

  const dim3 blk(256);
  const int gEA   = (EA + 255) / 256;
  const int gScan = (N + 255) / 256;
  const int gM    = (N + 127) / 128;
  const int gNode = (N + 3) / 4;

  cast_f2h<<<(N * 64 + 255) / 256, blk, 0, stream>>>(x, xa, N * 64);
  tcast_w<<<(65536 + 255) / 256, blk, 0, stream>>>(Wl0, Wr0, Bt0, 256, 128);
  tcast_w<<<(65536 + 255) / 256, blk, 0, stream>>>(Wl1, Wr1, Bt1, 128, 256);

  hipMemsetAsync(cnt, 0, (size_t)N * 4, stream);
  hipMemsetAsync(wo, 0, (size_t)N * 4, stream);
  csr_count<<<gEA, blk, 0, stream>>>(ei, E, EA, cnt);
  scan_block<<<gScan, blk, 0, stream>>>(cnt, rowptr, bsum, N);
  scan_top<<<1, blk, 0, stream>>>(bsum, bofs, gScan);
  scan_add<<<gScan, blk, 0, stream>>>(rowptr, bofs, N, EA);
  csr_fill<<<gEA, blk, 0, stream>>>(ei, E, EA, rowptr, wo, col);

  // Layer 0  (C=64, stride 256 halves -> LOGS=8, V=2)
  hgemm_tn<<<dim3(4, gM), blk, 0, stream>>>(xa, Bt0, feat0, N, 256, 256);
  fused_gat_h<64, 8, 2, 6, true, true><<<gNode, blk, 0, stream>>>(
      rowptr, col, feat0, att0, b0, ha, nullptr, N);

  // Layer 1  (C=128, stride 512 halves -> LOGS=9, V=4)
  hgemm_tn<<<dim3(8, gM), blk, 0, stream>>>(ha, Bt1, feat1, N, 512, 128);
  fused_gat_h<128, 9, 4, 6, false, false><<<gNode, blk, 0, stream>>>(
      rowptr, col, feat1, att1, b1, nullptr, out, N);
}

// Round 8
// 269.909 us; speedup vs baseline: 1.1974x; 1.0796x over previous
//
#include <hip/hip_runtime.h>
#include <cstdint>
#include <cstddef>

// GATv2 x2. Round 8: fused setup kernel; GEMM staged via global_load_lds with
// XOR-swizzled source + swizzled ds_read (padded-M unconditional staging);
// gat pipeline depth 6->4. N=50000, E=800000, H=2, C_IN=256, C1=64, C2=128.

#define NEG_SLOPE 0.2f

typedef _Float16 f16x8 __attribute__((ext_vector_type(8)));
typedef _Float16 f16x4 __attribute__((ext_vector_type(4)));
typedef _Float16 f16x2 __attribute__((ext_vector_type(2)));
typedef float f32x4 __attribute__((ext_vector_type(4)));

#if __has_builtin(__builtin_amdgcn_exp2f)
#define EXP2(x) __builtin_amdgcn_exp2f(x)
#else
#define EXP2(x) __expf((x)*0.69314718056f)
#endif

// x += dpp_perm(x). 0xB1=quad xor1, 0x4E=quad xor2, 0x124=row_ror:4, 0x128=row_ror:8
#define DPPADD(x, CTRL)                                                        \
  do {                                                                         \
    int _y = __builtin_amdgcn_update_dpp(0, __float_as_int(x), CTRL, 0xf, 0xf, \
                                         true);                                \
    x += __int_as_float(_y);                                                   \
  } while (0)

// global(16B, per-lane addr) -> LDS(wave-uniform base + lane*16). Fallback
// path reproduces identical layout via registers.
#if __has_builtin(__builtin_amdgcn_global_load_lds)
#define STAGE16(gp, lbase, lane)                                               \
  __builtin_amdgcn_global_load_lds(                                            \
      (const __attribute__((address_space(1))) void*)(gp),                     \
      (__attribute__((address_space(3))) void*)(lbase), 16, 0, 0)
#else
#define STAGE16(gp, lbase, lane)                                               \
  *(f16x8*)((lbase) + (size_t)(lane) * 8) = *(const f16x8*)(gp)
#endif

// ---------------------------------------------------------------------------
// Fused setup: [cast x->f16] + [W0^T cast] + [W1^T cast] + [zero cnt/wo]
__global__ __launch_bounds__(256) void setup_fused(
    const float* __restrict__ x, _Float16* __restrict__ xa,
    const float* __restrict__ Wl0, const float* __restrict__ Wr0,
    _Float16* __restrict__ Bt0,
    const float* __restrict__ Wl1, const float* __restrict__ Wr1,
    _Float16* __restrict__ Bt1,
    int* __restrict__ zptr, int zcount, int nb_cast, int N) {
  const int b = blockIdx.x;
  if (b < nb_cast) {
    const int t = b * 256 + threadIdx.x;
    if (t < N * 64) {
      const float4 v = *(const float4*)&x[(size_t)t * 4];
      f16x4 h;
      h[0] = (_Float16)v.x; h[1] = (_Float16)v.y;
      h[2] = (_Float16)v.z; h[3] = (_Float16)v.w;
      *(f16x4*)&xa[(size_t)t * 4] = h;
    }
  } else if (b < nb_cast + 256) {
    const int t = (b - nb_cast) * 256 + threadIdx.x;   // 0..65535
    const int n = t >> 8, k = t & 255;                 // K=256, NH=128
    const float v = (n < 128) ? Wl0[(size_t)k * 128 + n]
                              : Wr0[(size_t)k * 128 + (n - 128)];
    Bt0[t] = (_Float16)v;
  } else if (b < nb_cast + 512) {
    const int t = (b - nb_cast - 256) * 256 + threadIdx.x;  // 0..65535
    const int n = t >> 7, k = t & 127;                 // K=128, NH=256
    const float v = (n < 256) ? Wl1[(size_t)k * 256 + n]
                              : Wr1[(size_t)k * 256 + (n - 256)];
    Bt1[t] = (_Float16)v;
  } else {
    const int t = (b - nb_cast - 512) * 256 + threadIdx.x;
    if (t * 4 < zcount) *(int4*)&zptr[t * 4] = make_int4(0, 0, 0, 0);
  }
}

// ---------------------------------------------------------------------------
// C[M][NT](f16) = A[Mpad][K](f16) @ Bt[NT][K]^T. 128x64 tile, BK=64, 4 waves.
// Staging: global_load_lds, linear LDS [row][chunk], source chunk XOR-swizzled
// by (row&7); ds_read applies the same XOR. A reads are unconditional (padded).
__global__ __launch_bounds__(256) void hgemm_tn(
    const _Float16* __restrict__ A, const _Float16* __restrict__ Bt,
    _Float16* __restrict__ C, int M, int NT, int K) {
  __shared__ _Float16 As[128 * 64];   // [row][8 chunks of 8 halves]
  __shared__ _Float16 Bs[64 * 64];
  const int bm = blockIdx.y * 128;
  const int bn = blockIdx.x * 64;
  const int tid = threadIdx.x;
  const int lane = tid & 63;
  const int wave = tid >> 6;
  const int wr = (wave >> 1) * 64;
  const int wc = (wave & 1) * 32;
  const int l15 = lane & 15;
  const int kq8 = lane >> 4;          // fragment k-chunk 0..3
  const int srow = lane >> 3;         // staging row within 8-row group
  const int swz = (lane & 7) ^ srow;  // swizzled source chunk
  f32x4 acc[4][2] = {};
  for (int k0 = 0; k0 < K; k0 += 64) {
    __syncthreads();
#pragma unroll
    for (int i = 0; i < 4; ++i) {     // A: rows wave*32 + i*8 + srow
      const int r = wave * 32 + i * 8;
      const _Float16* gp = A + (size_t)(bm + r + srow) * K + k0 + swz * 8;
      STAGE16(gp, As + r * 64, lane);
    }
#pragma unroll
    for (int i = 0; i < 2; ++i) {     // B: rows wave*16 + i*8 + srow
      const int r = wave * 16 + i * 8;
      const _Float16* gp = Bt + (size_t)(bn + r + srow) * K + k0 + swz * 8;
      STAGE16(gp, Bs + r * 64, lane);
    }
    __syncthreads();
#pragma unroll
    for (int kk = 0; kk < 64; kk += 32) {
      const int oc = kq8 + (kk >> 3);
      f16x8 bf[2];
#pragma unroll
      for (int ni = 0; ni < 2; ++ni) {
        const int row = wc + ni * 16 + l15;
        bf[ni] = *(const f16x8*)&Bs[row * 64 + ((oc ^ (row & 7)) << 3)];
      }
#pragma unroll
      for (int mi = 0; mi < 4; ++mi) {
        const int row = wr + mi * 16 + l15;
        const f16x8 af = *(const f16x8*)&As[row * 64 + ((oc ^ (row & 7)) << 3)];
#pragma unroll
        for (int ni = 0; ni < 2; ++ni)
          acc[mi][ni] = __builtin_amdgcn_mfma_f32_16x16x32_f16(af, bf[ni], acc[mi][ni], 0, 0, 0);
      }
    }
  }
  const int crow0 = (lane >> 4) * 4;
#pragma unroll
  for (int mi = 0; mi < 4; ++mi) {
#pragma unroll
    for (int r = 0; r < 4; ++r) {
      const int row = bm + wr + mi * 16 + crow0 + r;
      if (row < M) {
#pragma unroll
        for (int ni = 0; ni < 2; ++ni)
          C[(size_t)row * NT + bn + wc + ni * 16 + l15] = (_Float16)acc[mi][ni][r];
      }
    }
  }
}

// ---------------------------------------------------------------------------
// CSR build (self-loops appended as (n->n)).
__global__ __launch_bounds__(256) void csr_count(
    const int* __restrict__ ei, int E, int EA, int* __restrict__ cnt) {
  const int i = blockIdx.x * blockDim.x + threadIdx.x;
  if (i >= EA) return;
  const int dst = (i < E) ? ei[E + i] : (i - E);
  atomicAdd(&cnt[dst], 1);
}

__global__ __launch_bounds__(256) void scan_block(
    const int* __restrict__ cnt, int* __restrict__ excl,
    int* __restrict__ bsum, int n) {
  __shared__ int s[256];
  const int tid = threadIdx.x;
  const int i = blockIdx.x * 256 + tid;
  const int v = (i < n) ? cnt[i] : 0;
  s[tid] = v;
  __syncthreads();
  for (int off = 1; off < 256; off <<= 1) {
    const int t = (tid >= off) ? s[tid - off] : 0;
    __syncthreads();
    s[tid] += t;
    __syncthreads();
  }
  if (i < n) excl[i] = s[tid] - v;
  if (tid == 255) bsum[blockIdx.x] = s[255];
}

__global__ __launch_bounds__(256) void scan_top(
    const int* __restrict__ bsum, int* __restrict__ bofs, int nb) {
  __shared__ int s[256];
  const int tid = threadIdx.x;
  const int v = (tid < nb) ? bsum[tid] : 0;
  s[tid] = v;
  __syncthreads();
  for (int off = 1; off < 256; off <<= 1) {
    const int t = (tid >= off) ? s[tid - off] : 0;
    __syncthreads();
    s[tid] += t;
    __syncthreads();
  }
  if (tid < nb) bofs[tid] = s[tid] - v;
}

__global__ __launch_bounds__(256) void scan_add(
    int* __restrict__ rowptr, const int* __restrict__ bofs, int n, int EA) {
  const int i = blockIdx.x * blockDim.x + threadIdx.x;
  if (i < n) rowptr[i] += bofs[i >> 8];
  if (i == 0) rowptr[n] = EA;
}

__global__ __launch_bounds__(256) void csr_fill(
    const int* __restrict__ ei, int E, int EA,
    const int* __restrict__ rowptr, int* __restrict__ wo,
    int* __restrict__ col) {
  const int i = blockIdx.x * blockDim.x + threadIdx.x;
  if (i >= EA) return;
  int src, dst;
  if (i < E) { src = ei[i]; dst = ei[E + i]; } else { src = dst = i - E; }
  const int pos = atomicAdd(&wo[dst], 1);
  col[rowptr[dst] + pos] = src;
}

// ---------------------------------------------------------------------------
// Fused per-node GATv2, 1 edge/wave, depth-D pipeline with unconditional
// clamped-index loads. exp2-domain softmax; att pre-scaled by log2(e).
template <int C, int LOGS, int V, int D, bool RELU, bool OUT16>
__global__ __launch_bounds__(256) void fused_gat_h(
    const int* __restrict__ rowptr, const int* __restrict__ col,
    const _Float16* __restrict__ feat, const float* __restrict__ att,
    const float* __restrict__ bias, _Float16* __restrict__ out16,
    float* __restrict__ out32, int N) {
  constexpr int P = V / 2;
  typedef _Float16 hv __attribute__((ext_vector_type(V)));
  const int n = blockIdx.x * 4 + (threadIdx.x >> 6);
  if (n >= N) return;
  const int lane = threadIdx.x & 63;
  const int h = lane >> 5;
  const int co = h * C + (lane & 31) * V;

  f16x2 xr2[P], at2[P];
  float O[V];
  {
    const int base = (n << LOGS) + 2 * C + co;
#pragma unroll
    for (int p = 0; p < P; ++p) xr2[p] = *(const f16x2*)&feat[base + 2 * p];
#pragma unroll
    for (int p = 0; p < P; ++p)
      at2[p] = f16x2{(_Float16)(att[co + 2 * p] * 1.44269504f),
                     (_Float16)(att[co + 2 * p + 1] * 1.44269504f)};
#pragma unroll
    for (int j = 0; j < V; ++j) O[j] = 0.f;
  }
  float m = -1e30f, l = 0.f;
  const int e0 = rowptr[n], e1 = rowptr[n + 1];
  const int e1m1 = e1 - 1;

  hv f[D];
  int cidx[D];
#pragma unroll
  for (int k = 0; k < D; ++k) {
    const int ek = e0 + k;
    const int ck = col[(ek < e1) ? ek : e1m1];
    f[k] = *(const hv*)&feat[(ck << LOGS) + co];
  }
#pragma unroll
  for (int k = 0; k < D; ++k) {
    const int ek = e0 + D + k;
    cidx[k] = col[(ek < e1) ? ek : e1m1];
  }

  for (int basee = e0; basee < e1; basee += D) {
#pragma unroll
    for (int k = 0; k < D; ++k) {
      const int eid = basee + k;
      const bool valid = eid < e1;
      float pacc = 0.f;
#pragma unroll
      for (int p = 0; p < P; ++p) {
        const f16x2 c2 = f16x2{f[k][2 * p], f[k][2 * p + 1]};
        const f16x2 s = c2 + xr2[p];
        const f16x2 mx = __builtin_elementwise_max(s, f16x2{(_Float16)0.f, (_Float16)0.f});
        const f16x2 mn = __builtin_elementwise_min(s, f16x2{(_Float16)0.f, (_Float16)0.f});
        const f16x2 lk = mn * f16x2{(_Float16)NEG_SLOPE, (_Float16)NEG_SLOPE} + mx;
        pacc = __builtin_amdgcn_fdot2(lk, at2[p], pacc, false);
      }
      DPPADD(pacc, 0xB1);
      DPPADD(pacc, 0x4E);
      DPPADD(pacc, 0x124);
      DPPADD(pacc, 0x128);
      pacc += __shfl_xor(pacc, 16, 64);
      if (!valid) pacc = -INFINITY;
      if (__any(pacc - m > 11.54f)) {
        const float mn2 = fmaxf(m, pacc);
        const float scale = EXP2(m - mn2);
        const float w = valid ? EXP2(pacc - mn2) : 0.f;
        l = l * scale + w;
#pragma unroll
        for (int j = 0; j < V; ++j) O[j] = O[j] * scale + w * (float)f[k][j];
        m = mn2;
      } else {
        const float w = EXP2(pacc - m);  // EXP2(-inf)=0 masks invalids
        l += w;
#pragma unroll
        for (int j = 0; j < V; ++j) O[j] += w * (float)f[k][j];
      }
      f[k] = *(const hv*)&feat[(cidx[k] << LOGS) + co];
      const int enn = eid + 2 * D;
      cidx[k] = col[(enn < e1) ? enn : e1m1];
    }
  }

  const float inv = 1.f / l;
  if constexpr (OUT16) {
    typedef _Float16 ov __attribute__((ext_vector_type(V)));
    ov o;
#pragma unroll
    for (int j = 0; j < V; ++j) {
      float v = O[j] * inv + bias[co + j];
      if constexpr (RELU) v = fmaxf(v, 0.f);
      o[j] = (_Float16)v;
    }
    *(ov*)&out16[n * (2 * C) + co] = o;
  } else {
    float4 o;
    o.x = O[0] * inv + bias[co + 0];
    o.y = O[1] * inv + bias[co + 1];
    o.z = O[2] * inv + bias[co + 2];
    o.w = O[3] * inv + bias[co + 3];
    *(float4*)&out32[(size_t)n * (2 * C) + co] = o;
  }
}

// ---------------------------------------------------------------------------
extern "C" void kernel_launch(void* const* d_in, const int* in_sizes, int n_in,
                              void* d_out, int out_size, void* d_ws, size_t ws_size,
                              hipStream_t stream) {
  const float* x    = (const float*)d_in[0];
  const int*   ei   = (const int*)d_in[1];
  const float* Wl0  = (const float*)d_in[2];
  const float* Wr0  = (const float*)d_in[3];
  const float* att0 = (const float*)d_in[4];
  const float* b0   = (const float*)d_in[5];
  const float* Wl1  = (const float*)d_in[6];
  const float* Wr1  = (const float*)d_in[7];
  const float* att1 = (const float*)d_in[8];
  const float* b1   = (const float*)d_in[9];
  float* out = (float*)d_out;

  const int N    = in_sizes[0] / 256;
  const int E    = in_sizes[1] / 2;
  const int EA   = E + N;
  const int Mpad = (N + 127) & ~127;   // padded rows for unconditional staging

  // Workspace (halves):
  //   feat1: N x 512 (feat0 = first N x 256, overlapped)
  //   ha:    Mpad x 128 (L0 out, f16; rows >= N are garbage, C-store guarded)
  //   xa:    Mpad x 256 (x in f16; rows >= N garbage)
  //   Bt0:   256 x 256, Bt1: 512 x 128
  //   ints:  rowptr[N+1] (padded to 4), cnt[N], wo[N], bsum[256], bofs[256], col[EA]
  _Float16* hw    = (_Float16*)d_ws;
  _Float16* feat0 = hw;
  _Float16* feat1 = hw;
  _Float16* ha    = hw + (size_t)N * 512;
  _Float16* xa    = ha + (size_t)Mpad * 128;
  _Float16* Bt0   = xa + (size_t)Mpad * 256;
  _Float16* Bt1   = Bt0 + 65536;
  int* rowptr = (int*)(Bt1 + 65536);
  const int cpad = (N + 1 + 3) & ~3;       // keep cnt 16-B aligned
  int* cnt    = rowptr + cpad;
  int* wo     = cnt + N;                   // contiguous with cnt
  int* bsum   = wo + N;
  int* bofs   = bsum + 256;
  int* col    = bofs + 256;

  const dim3 blk(256);
  const int gEA     = (EA + 255) / 256;
  const int gScan   = (N + 255) / 256;
  const int gM      = Mpad / 128;
  const int gNode   = (N + 3) / 4;
  const int nb_cast = (N * 64 + 255) / 256;
  const int zcount  = 2 * N;               // cnt + wo
  const int nb_zero = (zcount / 4 + 255) / 256;

  // fused setup: cast x, transpose+cast W0/W1, zero cnt+wo
  setup_fused<<<nb_cast + 512 + nb_zero, blk, 0, stream>>>(
      x, xa, Wl0, Wr0, Bt0, Wl1, Wr1, Bt1, cnt, zcount, nb_cast, N);

  // CSR build
  csr_count<<<gEA, blk, 0, stream>>>(ei, E, EA, cnt);
  scan_block<<<gScan, blk, 0, stream>>>(cnt, rowptr, bsum, N);
  scan_top<<<1, blk, 0, stream>>>(bsum, bofs, gScan);
  scan_add<<<gScan, blk, 0, stream>>>(rowptr, bofs, N, EA);
  csr_fill<<<gEA, blk, 0, stream>>>(ei, E, EA, rowptr, wo, col);

  // Layer 0  (C=64, stride 256 halves -> LOGS=8, V=2)
  hgemm_tn<<<dim3(4, gM), blk, 0, stream>>>(xa, Bt0, feat0, N, 256, 256);
  fused_gat_h<64, 8, 2, 4, true, true><<<gNode, blk, 0, stream>>>(
      rowptr, col, feat0, att0, b0, ha, nullptr, N);

  // Layer 1  (C=128, stride 512 halves -> LOGS=9, V=4)
  hgemm_tn<<<dim3(8, gM), blk, 0, stream>>>(ha, Bt1, feat1, N, 512, 128);
  fused_gat_h<128, 9, 4, 4, false, false><<<gNode, blk, 0, stream>>>(
      rowptr, col, feat1, att1, b1, nullptr, out, N);
}

// Round 9
// 260.916 us; speedup vs baseline: 1.2386x; 1.0345x over previous
//
#include <hip/hip_runtime.h>
#include <cstdint>
#include <cstddef>

// GATv2 x2. Round 9: 2 edges per wave (two 32-lane halves, independent online
// softmax streams, 4-step row-local DPP reduce, final half-merge), dispatch
// fusion (count->setup, fill->gemm0, wo-zero->scan_block). 9 dispatches.
// N=50000, E=800000, H=2, C_IN=256, C1=64, C2=128.

#define NEG_SLOPE 0.2f

typedef _Float16 f16x8 __attribute__((ext_vector_type(8)));
typedef _Float16 f16x4 __attribute__((ext_vector_type(4)));
typedef _Float16 f16x2 __attribute__((ext_vector_type(2)));
typedef float f32x4 __attribute__((ext_vector_type(4)));

#if __has_builtin(__builtin_amdgcn_exp2f)
#define EXP2(x) __builtin_amdgcn_exp2f(x)
#else
#define EXP2(x) __expf((x)*0.69314718056f)
#endif

// x += dpp_perm(x). 0xB1=quad xor1, 0x4E=quad xor2, 0x124=row_ror:4, 0x128=row_ror:8
#define DPPADD(x, CTRL)                                                        \
  do {                                                                         \
    int _y = __builtin_amdgcn_update_dpp(0, __float_as_int(x), CTRL, 0xf, 0xf, \
                                         true);                                \
    x += __int_as_float(_y);                                                   \
  } while (0)

// global(16B, per-lane addr) -> LDS(wave-uniform base + lane*16).
#if __has_builtin(__builtin_amdgcn_global_load_lds)
#define STAGE16(gp, lbase, lane)                                               \
  __builtin_amdgcn_global_load_lds(                                            \
      (const __attribute__((address_space(1))) void*)(gp),                     \
      (__attribute__((address_space(3))) void*)(lbase), 16, 0, 0)
#else
#define STAGE16(gp, lbase, lane)                                               \
  *(f16x8*)((lbase) + (size_t)(lane) * 8) = *(const f16x8*)(gp)
#endif

// ---------------------------------------------------------------------------
// Fused setup: [cast x->f16] + [W0^T cast] + [W1^T cast] + [csr_count]
// (cnt must be zeroed by a preceding memset)
__global__ __launch_bounds__(256) void setup_fused(
    const float* __restrict__ x, _Float16* __restrict__ xa,
    const float* __restrict__ Wl0, const float* __restrict__ Wr0,
    _Float16* __restrict__ Bt0,
    const float* __restrict__ Wl1, const float* __restrict__ Wr1,
    _Float16* __restrict__ Bt1,
    const int* __restrict__ ei, int E, int EA, int* __restrict__ cnt,
    int nb_cast, int N) {
  const int b = blockIdx.x;
  if (b < nb_cast) {
    const int t = b * 256 + threadIdx.x;
    if (t < N * 64) {
      const float4 v = *(const float4*)&x[(size_t)t * 4];
      f16x4 h;
      h[0] = (_Float16)v.x; h[1] = (_Float16)v.y;
      h[2] = (_Float16)v.z; h[3] = (_Float16)v.w;
      *(f16x4*)&xa[(size_t)t * 4] = h;
    }
  } else if (b < nb_cast + 256) {
    const int t = (b - nb_cast) * 256 + threadIdx.x;   // 0..65535
    const int n = t >> 8, k = t & 255;                 // K=256, NH=128
    const float v = (n < 128) ? Wl0[(size_t)k * 128 + n]
                              : Wr0[(size_t)k * 128 + (n - 128)];
    Bt0[t] = (_Float16)v;
  } else if (b < nb_cast + 512) {
    const int t = (b - nb_cast - 256) * 256 + threadIdx.x;  // 0..65535
    const int n = t >> 7, k = t & 127;                 // K=128, NH=256
    const float v = (n < 256) ? Wl1[(size_t)k * 256 + n]
                              : Wr1[(size_t)k * 256 + (n - 256)];
    Bt1[t] = (_Float16)v;
  } else {
    const int i = (b - nb_cast - 512) * 256 + threadIdx.x;
    if (i < EA) {
      const int dst = (i < E) ? ei[E + i] : (i - E);
      atomicAdd(&cnt[dst], 1);
    }
  }
}

// ---------------------------------------------------------------------------
// Shared GEMM body: C[M][NT](f16) = A[Mpad][K](f16) @ Bt[NT][K]^T.
// 128x64 tile, BK=64, 4 waves. global_load_lds staging, XOR-swizzled source
// chunk + same XOR on ds_read (A reads unconditional: M padded).
__device__ __forceinline__ void hgemm_body(
    const _Float16* __restrict__ A, const _Float16* __restrict__ Bt,
    _Float16* __restrict__ C, int M, int NT, int K, int bm, int bn) {
  __shared__ _Float16 As[128 * 64];   // [row][8 chunks of 8 halves]
  __shared__ _Float16 Bs[64 * 64];
  const int tid = threadIdx.x;
  const int lane = tid & 63;
  const int wave = tid >> 6;
  const int wr = (wave >> 1) * 64;
  const int wc = (wave & 1) * 32;
  const int l15 = lane & 15;
  const int kq8 = lane >> 4;          // fragment k-chunk 0..3
  const int srow = lane >> 3;         // staging row within 8-row group
  const int swz = (lane & 7) ^ srow;  // swizzled source chunk
  f32x4 acc[4][2] = {};
  for (int k0 = 0; k0 < K; k0 += 64) {
    __syncthreads();
#pragma unroll
    for (int i = 0; i < 4; ++i) {     // A: rows wave*32 + i*8 + srow
      const int r = wave * 32 + i * 8;
      const _Float16* gp = A + (size_t)(bm + r + srow) * K + k0 + swz * 8;
      STAGE16(gp, As + r * 64, lane);
    }
#pragma unroll
    for (int i = 0; i < 2; ++i) {     // B: rows wave*16 + i*8 + srow
      const int r = wave * 16 + i * 8;
      const _Float16* gp = Bt + (size_t)(bn + r + srow) * K + k0 + swz * 8;
      STAGE16(gp, Bs + r * 64, lane);
    }
    __syncthreads();
#pragma unroll
    for (int kk = 0; kk < 64; kk += 32) {
      const int oc = kq8 + (kk >> 3);
      f16x8 bf[2];
#pragma unroll
      for (int ni = 0; ni < 2; ++ni) {
        const int row = wc + ni * 16 + l15;
        bf[ni] = *(const f16x8*)&Bs[row * 64 + ((oc ^ (row & 7)) << 3)];
      }
#pragma unroll
      for (int mi = 0; mi < 4; ++mi) {
        const int row = wr + mi * 16 + l15;
        const f16x8 af = *(const f16x8*)&As[row * 64 + ((oc ^ (row & 7)) << 3)];
#pragma unroll
        for (int ni = 0; ni < 2; ++ni)
          acc[mi][ni] = __builtin_amdgcn_mfma_f32_16x16x32_f16(af, bf[ni], acc[mi][ni], 0, 0, 0);
      }
    }
  }
  const int crow0 = (lane >> 4) * 4;
#pragma unroll
  for (int mi = 0; mi < 4; ++mi) {
#pragma unroll
    for (int r = 0; r < 4; ++r) {
      const int row = bm + wr + mi * 16 + crow0 + r;
      if (row < M) {
#pragma unroll
        for (int ni = 0; ni < 2; ++ni)
          C[(size_t)row * NT + bn + wc + ni * 16 + l15] = (_Float16)acc[mi][ni][r];
      }
    }
  }
}

__global__ __launch_bounds__(256) void hgemm_tn(
    const _Float16* __restrict__ A, const _Float16* __restrict__ Bt,
    _Float16* __restrict__ C, int M, int NT, int K) {
  hgemm_body(A, Bt, C, M, NT, K, blockIdx.y * 128, blockIdx.x * 64);
}

// gemm0 fused with csr_fill (independent work, grid-partitioned; NT=256 -> 4 n-blocks)
__global__ __launch_bounds__(256) void gemm_fill(
    const _Float16* __restrict__ A, const _Float16* __restrict__ Bt,
    _Float16* __restrict__ C, int M, int NT, int K,
    const int* __restrict__ ei, int E, int EA,
    const int* __restrict__ rowptr, int* __restrict__ wo,
    int* __restrict__ col, int gFill) {
  if ((int)blockIdx.x < gFill) {
    const int i = blockIdx.x * 256 + threadIdx.x;
    if (i < EA) {
      int src, dst;
      if (i < E) { src = ei[i]; dst = ei[E + i]; } else { src = dst = i - E; }
      const int pos = atomicAdd(&wo[dst], 1);
      col[rowptr[dst] + pos] = src;
    }
    return;
  }
  const int b2 = blockIdx.x - gFill;
  hgemm_body(A, Bt, C, M, NT, K, (b2 >> 2) * 128, (b2 & 3) * 64);
}

// ---------------------------------------------------------------------------
// CSR scan kernels
__global__ __launch_bounds__(256) void scan_block(
    const int* __restrict__ cnt, int* __restrict__ excl,
    int* __restrict__ bsum, int* __restrict__ wo, int n) {
  __shared__ int s[256];
  const int tid = threadIdx.x;
  const int i = blockIdx.x * 256 + tid;
  const int v = (i < n) ? cnt[i] : 0;
  s[tid] = v;
  __syncthreads();
  for (int off = 1; off < 256; off <<= 1) {
    const int t = (tid >= off) ? s[tid - off] : 0;
    __syncthreads();
    s[tid] += t;
    __syncthreads();
  }
  if (i < n) { excl[i] = s[tid] - v; wo[i] = 0; }
  if (tid == 255) bsum[blockIdx.x] = s[255];
}

__global__ __launch_bounds__(256) void scan_top(
    const int* __restrict__ bsum, int* __restrict__ bofs, int nb) {
  __shared__ int s[256];
  const int tid = threadIdx.x;
  const int v = (tid < nb) ? bsum[tid] : 0;
  s[tid] = v;
  __syncthreads();
  for (int off = 1; off < 256; off <<= 1) {
    const int t = (tid >= off) ? s[tid - off] : 0;
    __syncthreads();
    s[tid] += t;
    __syncthreads();
  }
  if (tid < nb) bofs[tid] = s[tid] - v;
}

__global__ __launch_bounds__(256) void scan_add(
    int* __restrict__ rowptr, const int* __restrict__ bofs, int n, int EA) {
  const int i = blockIdx.x * blockDim.x + threadIdx.x;
  if (i < n) rowptr[i] += bofs[i >> 8];
  if (i == 0) rowptr[n] = EA;
}

// ---------------------------------------------------------------------------
// Fused per-node GATv2, 2 edges per wave. half = lane>>5 owns edge stream
// e0+half, e0+half+2, ... with its own (m,l,O); li = lane&31 holds V = 2C/32
// channels (co = li*V; head boundary at li=16). Logit reduce = 4 row-local
// DPP steps (16-lane head rows). Depth-D unconditional clamped pipeline.
// Final cross-half merge; lanes 0-31 write. att pre-scaled by log2(e).
template <int C, int LOGS, int V, int D, bool RELU, bool OUT16>
__global__ __launch_bounds__(256) void fused_gat_h2(
    const int* __restrict__ rowptr, const int* __restrict__ col,
    const _Float16* __restrict__ feat, const float* __restrict__ att,
    const float* __restrict__ bias, _Float16* __restrict__ out16,
    float* __restrict__ out32, int N) {
  constexpr int P = V / 2;
  typedef _Float16 hv __attribute__((ext_vector_type(V)));
  const int n = blockIdx.x * 4 + (threadIdx.x >> 6);
  if (n >= N) return;
  const int lane = threadIdx.x & 63;
  const int half = lane >> 5;
  const int li = lane & 31;
  const int co = li * V;                 // channel offset in [0, 2C)

  f16x2 xr2[P], at2[P];
  float O[V];
  {
    const int base = (n << LOGS) + 2 * C + co;
#pragma unroll
    for (int p = 0; p < P; ++p) xr2[p] = *(const f16x2*)&feat[base + 2 * p];
#pragma unroll
    for (int p = 0; p < P; ++p)
      at2[p] = f16x2{(_Float16)(att[co + 2 * p] * 1.44269504f),
                     (_Float16)(att[co + 2 * p + 1] * 1.44269504f)};
#pragma unroll
    for (int j = 0; j < V; ++j) O[j] = 0.f;
  }
  float m = -1e30f, l = 0.f;
  const int e0 = rowptr[n], e1 = rowptr[n + 1];
  const int e1m1 = e1 - 1;

  hv f[D];
  int cidx[D];
#pragma unroll
  for (int k = 0; k < D; ++k) {
    const int ek = e0 + 2 * k + half;
    const int ck = col[(ek < e1) ? ek : e1m1];
    f[k] = *(const hv*)&feat[(ck << LOGS) + co];
  }
#pragma unroll
  for (int k = 0; k < D; ++k) {
    const int ek = e0 + 2 * k + half + 2 * D;
    cidx[k] = col[(ek < e1) ? ek : e1m1];
  }

  for (int ebase = e0; ebase < e1; ebase += 2 * D) {
#pragma unroll
    for (int k = 0; k < D; ++k) {
      const int eid = ebase + 2 * k + half;
      const bool valid = eid < e1;
      float pacc = 0.f;
#pragma unroll
      for (int p = 0; p < P; ++p) {
        const f16x2 c2 = f16x2{f[k][2 * p], f[k][2 * p + 1]};
        const f16x2 s = c2 + xr2[p];
        const f16x2 mx = __builtin_elementwise_max(s, f16x2{(_Float16)0.f, (_Float16)0.f});
        const f16x2 mn = __builtin_elementwise_min(s, f16x2{(_Float16)0.f, (_Float16)0.f});
        const f16x2 lk = mn * f16x2{(_Float16)NEG_SLOPE, (_Float16)NEG_SLOPE} + mx;
        pacc = __builtin_amdgcn_fdot2(lk, at2[p], pacc, false);
      }
      // reduce over my 16-lane head row (row-local DPP only, serves 2 edges)
      DPPADD(pacc, 0xB1);
      DPPADD(pacc, 0x4E);
      DPPADD(pacc, 0x124);
      DPPADD(pacc, 0x128);
      if (!valid) pacc = -INFINITY;   // -> w = EXP2(-inf) = 0 below
      if (__any(pacc - m > 11.54f)) {
        const float mn2 = fmaxf(m, pacc);
        const float scale = EXP2(m - mn2);
        const float w = EXP2(pacc - mn2);
        l = l * scale + w;
#pragma unroll
        for (int j = 0; j < V; ++j) O[j] = O[j] * scale + w * (float)f[k][j];
        m = mn2;
      } else {
        const float w = EXP2(pacc - m);
        l += w;
#pragma unroll
        for (int j = 0; j < V; ++j) O[j] += w * (float)f[k][j];
      }
      f[k] = *(const hv*)&feat[(cidx[k] << LOGS) + co];
      const int enn = eid + 4 * D;
      cidx[k] = col[(enn < e1) ? enn : e1m1];
    }
  }

  // merge the two half-wave softmax states (lane L <-> L^32)
  {
    const float m2 = __shfl_xor(m, 32, 64);
    const float l2 = __shfl_xor(l, 32, 64);
    const float mn = fmaxf(m, m2);
    const float s1 = EXP2(m - mn);
    const float s2 = EXP2(m2 - mn);
    l = l * s1 + l2 * s2;
#pragma unroll
    for (int j = 0; j < V; ++j)
      O[j] = O[j] * s1 + __shfl_xor(O[j], 32, 64) * s2;
  }
  if (half) return;                     // lanes 0-31 hold the merged result

  const float inv = 1.f / l;
  if constexpr (OUT16) {
    typedef _Float16 ov __attribute__((ext_vector_type(V)));
    ov o;
#pragma unroll
    for (int j = 0; j < V; ++j) {
      float v = O[j] * inv + bias[co + j];
      if constexpr (RELU) v = fmaxf(v, 0.f);
      o[j] = (_Float16)v;
    }
    *(ov*)&out16[n * (2 * C) + co] = o;
  } else {
#pragma unroll
    for (int q = 0; q < V / 4; ++q) {
      float4 o;
      o.x = O[q * 4 + 0] * inv + bias[co + q * 4 + 0];
      o.y = O[q * 4 + 1] * inv + bias[co + q * 4 + 1];
      o.z = O[q * 4 + 2] * inv + bias[co + q * 4 + 2];
      o.w = O[q * 4 + 3] * inv + bias[co + q * 4 + 3];
      *(float4*)&out32[(size_t)n * (2 * C) + co + q * 4] = o;
    }
  }
}

// ---------------------------------------------------------------------------
extern "C" void kernel_launch(void* const* d_in, const int* in_sizes, int n_in,
                              void* d_out, int out_size, void* d_ws, size_t ws_size,
                              hipStream_t stream) {
  const float* x    = (const float*)d_in[0];
  const int*   ei   = (const int*)d_in[1];
  const float* Wl0  = (const float*)d_in[2];
  const float* Wr0  = (const float*)d_in[3];
  const float* att0 = (const float*)d_in[4];
  const float* b0   = (const float*)d_in[5];
  const float* Wl1  = (const float*)d_in[6];
  const float* Wr1  = (const float*)d_in[7];
  const float* att1 = (const float*)d_in[8];
  const float* b1   = (const float*)d_in[9];
  float* out = (float*)d_out;

  const int N    = in_sizes[0] / 256;
  const int E    = in_sizes[1] / 2;
  const int EA   = E + N;
  const int Mpad = (N + 127) & ~127;   // padded rows for unconditional staging

  _Float16* hw    = (_Float16*)d_ws;
  _Float16* feat0 = hw;                       // N x 256 (overlapped by feat1)
  _Float16* feat1 = hw;                       // N x 512
  _Float16* ha    = hw + (size_t)N * 512;     // Mpad x 128 (L0 out, f16)
  _Float16* xa    = ha + (size_t)Mpad * 128;  // Mpad x 256 (x in f16)
  _Float16* Bt0   = xa + (size_t)Mpad * 256;  // 256 x 256
  _Float16* Bt1   = Bt0 + 65536;              // 512 x 128
  int* rowptr = (int*)(Bt1 + 65536);
  const int cpad = (N + 1 + 3) & ~3;
  int* cnt    = rowptr + cpad;
  int* wo     = cnt + N;
  int* bsum   = wo + N;
  int* bofs   = bsum + 256;
  int* col    = bofs + 256;

  const dim3 blk(256);
  const int gEA     = (EA + 255) / 256;
  const int gScan   = (N + 255) / 256;
  const int gM      = Mpad / 128;
  const int gNode   = (N + 3) / 4;
  const int nb_cast = (N * 64 + 255) / 256;

  // 1) zero cnt (count atomics come next dispatch)
  hipMemsetAsync(cnt, 0, (size_t)N * 4, stream);
  // 2) fused setup: cast x, transpose+cast W0/W1, csr_count
  setup_fused<<<nb_cast + 512 + gEA, blk, 0, stream>>>(
      x, xa, Wl0, Wr0, Bt0, Wl1, Wr1, Bt1, ei, E, EA, cnt, nb_cast, N);
  // 3-5) scan chain (scan_block also zeroes wo)
  scan_block<<<gScan, blk, 0, stream>>>(cnt, rowptr, bsum, wo, N);
  scan_top<<<1, blk, 0, stream>>>(bsum, bofs, gScan);
  scan_add<<<gScan, blk, 0, stream>>>(rowptr, bofs, N, EA);
  // 6) csr_fill (first gEA blocks) overlapped with gemm0
  gemm_fill<<<gEA + 4 * gM, blk, 0, stream>>>(
      xa, Bt0, feat0, N, 256, 256, ei, E, EA, rowptr, wo, col, gEA);
  // 7) gat0 (C=64, stride 256 halves -> LOGS=8, V=4)
  fused_gat_h2<64, 8, 4, 4, true, true><<<gNode, blk, 0, stream>>>(
      rowptr, col, feat0, att0, b0, ha, nullptr, N);
  // 8) gemm1
  hgemm_tn<<<dim3(8, gM), blk, 0, stream>>>(ha, Bt1, feat1, N, 512, 128);
  // 9) gat1 (C=128, stride 512 halves -> LOGS=9, V=8)
  fused_gat_h2<128, 9, 8, 4, false, false><<<gNode, blk, 0, stream>>>(
      rowptr, col, feat1, att1, b1, nullptr, out, N);
}

// Round 10
// 248.545 us; speedup vs baseline: 1.3003x; 1.0498x over previous
//
#include <hip/hip_runtime.h>
#include <cstdint>
#include <cstddef>

// GATv2 x2. Round 10: GEMM 128x128 tile (BK=64, 4 waves, 64x64/wave),
// scan_top folded into scan_add. 8 dispatches. gat kernels unchanged from R9.
// N=50000, E=800000, H=2, C_IN=256, C1=64, C2=128.

#define NEG_SLOPE 0.2f

typedef _Float16 f16x8 __attribute__((ext_vector_type(8)));
typedef _Float16 f16x4 __attribute__((ext_vector_type(4)));
typedef _Float16 f16x2 __attribute__((ext_vector_type(2)));
typedef float f32x4 __attribute__((ext_vector_type(4)));

#if __has_builtin(__builtin_amdgcn_exp2f)
#define EXP2(x) __builtin_amdgcn_exp2f(x)
#else
#define EXP2(x) __expf((x)*0.69314718056f)
#endif

// x += dpp_perm(x). 0xB1=quad xor1, 0x4E=quad xor2, 0x124=row_ror:4, 0x128=row_ror:8
#define DPPADD(x, CTRL)                                                        \
  do {                                                                         \
    int _y = __builtin_amdgcn_update_dpp(0, __float_as_int(x), CTRL, 0xf, 0xf, \
                                         true);                                \
    x += __int_as_float(_y);                                                   \
  } while (0)

// global(16B, per-lane addr) -> LDS(wave-uniform base + lane*16).
#if __has_builtin(__builtin_amdgcn_global_load_lds)
#define STAGE16(gp, lbase, lane)                                               \
  __builtin_amdgcn_global_load_lds(                                            \
      (const __attribute__((address_space(1))) void*)(gp),                     \
      (__attribute__((address_space(3))) void*)(lbase), 16, 0, 0)
#else
#define STAGE16(gp, lbase, lane)                                               \
  *(f16x8*)((lbase) + (size_t)(lane) * 8) = *(const f16x8*)(gp)
#endif

// ---------------------------------------------------------------------------
// Fused setup: [cast x->f16] + [W0^T cast] + [W1^T cast] + [csr_count]
// (cnt must be zeroed by a preceding memset)
__global__ __launch_bounds__(256) void setup_fused(
    const float* __restrict__ x, _Float16* __restrict__ xa,
    const float* __restrict__ Wl0, const float* __restrict__ Wr0,
    _Float16* __restrict__ Bt0,
    const float* __restrict__ Wl1, const float* __restrict__ Wr1,
    _Float16* __restrict__ Bt1,
    const int* __restrict__ ei, int E, int EA, int* __restrict__ cnt,
    int nb_cast, int N) {
  const int b = blockIdx.x;
  if (b < nb_cast) {
    const int t = b * 256 + threadIdx.x;
    if (t < N * 64) {
      const float4 v = *(const float4*)&x[(size_t)t * 4];
      f16x4 h;
      h[0] = (_Float16)v.x; h[1] = (_Float16)v.y;
      h[2] = (_Float16)v.z; h[3] = (_Float16)v.w;
      *(f16x4*)&xa[(size_t)t * 4] = h;
    }
  } else if (b < nb_cast + 256) {
    const int t = (b - nb_cast) * 256 + threadIdx.x;   // 0..65535
    const int n = t >> 8, k = t & 255;                 // K=256, NH=128
    const float v = (n < 128) ? Wl0[(size_t)k * 128 + n]
                              : Wr0[(size_t)k * 128 + (n - 128)];
    Bt0[t] = (_Float16)v;
  } else if (b < nb_cast + 512) {
    const int t = (b - nb_cast - 256) * 256 + threadIdx.x;  // 0..65535
    const int n = t >> 7, k = t & 127;                 // K=128, NH=256
    const float v = (n < 256) ? Wl1[(size_t)k * 256 + n]
                              : Wr1[(size_t)k * 256 + (n - 256)];
    Bt1[t] = (_Float16)v;
  } else {
    const int i = (b - nb_cast - 512) * 256 + threadIdx.x;
    if (i < EA) {
      const int dst = (i < E) ? ei[E + i] : (i - E);
      atomicAdd(&cnt[dst], 1);
    }
  }
}

// ---------------------------------------------------------------------------
// Shared GEMM body: C[M][NT](f16) = A[Mpad][K](f16) @ Bt[NT][K]^T.
// 128x128 tile, BK=64, 4 waves, each wave 64x64 out. global_load_lds staging,
// XOR-swizzled source chunk + same XOR on ds_read. A/B reads unconditional
// (M padded; NT multiple of 128).
__device__ __forceinline__ void hgemm_body(
    const _Float16* __restrict__ A, const _Float16* __restrict__ Bt,
    _Float16* __restrict__ C, int M, int NT, int K, int bm, int bn) {
  __shared__ _Float16 As[128 * 64];   // [row][8 chunks of 8 halves]
  __shared__ _Float16 Bs[128 * 64];
  const int tid = threadIdx.x;
  const int lane = tid & 63;
  const int wave = tid >> 6;
  const int wr = (wave >> 1) * 64;    // wave row offset
  const int wcol = (wave & 1) * 64;   // wave col offset
  const int l15 = lane & 15;
  const int kq8 = lane >> 4;          // fragment k-chunk 0..3
  const int srow = lane >> 3;         // staging row within 8-row group
  const int swz = (lane & 7) ^ srow;  // swizzled source chunk
  f32x4 acc[4][4] = {};
  for (int k0 = 0; k0 < K; k0 += 64) {
    __syncthreads();
#pragma unroll
    for (int i = 0; i < 4; ++i) {     // A rows: wave*32 + i*8 + srow
      const int r = wave * 32 + i * 8;
      const _Float16* gp = A + (size_t)(bm + r + srow) * K + k0 + swz * 8;
      STAGE16(gp, As + r * 64, lane);
    }
#pragma unroll
    for (int i = 0; i < 4; ++i) {     // B rows: wave*32 + i*8 + srow
      const int r = wave * 32 + i * 8;
      const _Float16* gp = Bt + (size_t)(bn + r + srow) * K + k0 + swz * 8;
      STAGE16(gp, Bs + r * 64, lane);
    }
    __syncthreads();
#pragma unroll
    for (int kk = 0; kk < 64; kk += 32) {
      const int oc = kq8 + (kk >> 3);
      f16x8 bf[4];
#pragma unroll
      for (int ni = 0; ni < 4; ++ni) {
        const int row = wcol + ni * 16 + l15;
        bf[ni] = *(const f16x8*)&Bs[row * 64 + ((oc ^ (row & 7)) << 3)];
      }
#pragma unroll
      for (int mi = 0; mi < 4; ++mi) {
        const int row = wr + mi * 16 + l15;
        const f16x8 af = *(const f16x8*)&As[row * 64 + ((oc ^ (row & 7)) << 3)];
#pragma unroll
        for (int ni = 0; ni < 4; ++ni)
          acc[mi][ni] = __builtin_amdgcn_mfma_f32_16x16x32_f16(af, bf[ni], acc[mi][ni], 0, 0, 0);
      }
    }
  }
  const int crow0 = (lane >> 4) * 4;
#pragma unroll
  for (int mi = 0; mi < 4; ++mi) {
#pragma unroll
    for (int r = 0; r < 4; ++r) {
      const int row = bm + wr + mi * 16 + crow0 + r;
      if (row < M) {
#pragma unroll
        for (int ni = 0; ni < 4; ++ni)
          C[(size_t)row * NT + bn + wcol + ni * 16 + l15] = (_Float16)acc[mi][ni][r];
      }
    }
  }
}

__global__ __launch_bounds__(256) void hgemm_tn(
    const _Float16* __restrict__ A, const _Float16* __restrict__ Bt,
    _Float16* __restrict__ C, int M, int NT, int K) {
  hgemm_body(A, Bt, C, M, NT, K, blockIdx.y * 128, blockIdx.x * 128);
}

// gemm0 fused with csr_fill (independent work, grid-partitioned; NT=256 -> 2 n-blocks)
__global__ __launch_bounds__(256) void gemm_fill(
    const _Float16* __restrict__ A, const _Float16* __restrict__ Bt,
    _Float16* __restrict__ C, int M, int NT, int K,
    const int* __restrict__ ei, int E, int EA,
    const int* __restrict__ rowptr, int* __restrict__ wo,
    int* __restrict__ col, int gFill) {
  if ((int)blockIdx.x < gFill) {
    const int i = blockIdx.x * 256 + threadIdx.x;
    if (i < EA) {
      int src, dst;
      if (i < E) { src = ei[i]; dst = ei[E + i]; } else { src = dst = i - E; }
      const int pos = atomicAdd(&wo[dst], 1);
      col[rowptr[dst] + pos] = src;
    }
    return;
  }
  const int b2 = blockIdx.x - gFill;
  hgemm_body(A, Bt, C, M, NT, K, (b2 >> 1) * 128, (b2 & 1) * 128);
}

// ---------------------------------------------------------------------------
// CSR scan kernels
__global__ __launch_bounds__(256) void scan_block(
    const int* __restrict__ cnt, int* __restrict__ excl,
    int* __restrict__ bsum, int* __restrict__ wo, int n) {
  __shared__ int s[256];
  const int tid = threadIdx.x;
  const int i = blockIdx.x * 256 + tid;
  const int v = (i < n) ? cnt[i] : 0;
  s[tid] = v;
  __syncthreads();
  for (int off = 1; off < 256; off <<= 1) {
    const int t = (tid >= off) ? s[tid - off] : 0;
    __syncthreads();
    s[tid] += t;
    __syncthreads();
  }
  if (i < n) { excl[i] = s[tid] - v; wo[i] = 0; }
  if (tid == 255) bsum[blockIdx.x] = s[255];
}

// adds prefix of bsum[0..blockIdx.x) to this block's rowptr entries
// (folds the old scan_top into scan_add; nb <= 256)
__global__ __launch_bounds__(256) void scan_add(
    int* __restrict__ rowptr, const int* __restrict__ bsum, int n, int EA) {
  __shared__ int s[256];
  const int tid = threadIdx.x;
  s[tid] = (tid < (int)blockIdx.x) ? bsum[tid] : 0;
  __syncthreads();
#pragma unroll
  for (int off = 128; off; off >>= 1) {
    if (tid < off) s[tid] += s[tid + off];
    __syncthreads();
  }
  const int add = s[0];
  const int i = blockIdx.x * 256 + tid;
  if (i < n) rowptr[i] += add;
  if (i == 0) rowptr[n] = EA;
}

// ---------------------------------------------------------------------------
// Fused per-node GATv2, 2 edges per wave (unchanged from R9).
template <int C, int LOGS, int V, int D, bool RELU, bool OUT16>
__global__ __launch_bounds__(256) void fused_gat_h2(
    const int* __restrict__ rowptr, const int* __restrict__ col,
    const _Float16* __restrict__ feat, const float* __restrict__ att,
    const float* __restrict__ bias, _Float16* __restrict__ out16,
    float* __restrict__ out32, int N) {
  constexpr int P = V / 2;
  typedef _Float16 hv __attribute__((ext_vector_type(V)));
  const int n = blockIdx.x * 4 + (threadIdx.x >> 6);
  if (n >= N) return;
  const int lane = threadIdx.x & 63;
  const int half = lane >> 5;
  const int li = lane & 31;
  const int co = li * V;                 // channel offset in [0, 2C)

  f16x2 xr2[P], at2[P];
  float O[V];
  {
    const int base = (n << LOGS) + 2 * C + co;
#pragma unroll
    for (int p = 0; p < P; ++p) xr2[p] = *(const f16x2*)&feat[base + 2 * p];
#pragma unroll
    for (int p = 0; p < P; ++p)
      at2[p] = f16x2{(_Float16)(att[co + 2 * p] * 1.44269504f),
                     (_Float16)(att[co + 2 * p + 1] * 1.44269504f)};
#pragma unroll
    for (int j = 0; j < V; ++j) O[j] = 0.f;
  }
  float m = -1e30f, l = 0.f;
  const int e0 = rowptr[n], e1 = rowptr[n + 1];
  const int e1m1 = e1 - 1;

  hv f[D];
  int cidx[D];
#pragma unroll
  for (int k = 0; k < D; ++k) {
    const int ek = e0 + 2 * k + half;
    const int ck = col[(ek < e1) ? ek : e1m1];
    f[k] = *(const hv*)&feat[(ck << LOGS) + co];
  }
#pragma unroll
  for (int k = 0; k < D; ++k) {
    const int ek = e0 + 2 * k + half + 2 * D;
    cidx[k] = col[(ek < e1) ? ek : e1m1];
  }

  for (int ebase = e0; ebase < e1; ebase += 2 * D) {
#pragma unroll
    for (int k = 0; k < D; ++k) {
      const int eid = ebase + 2 * k + half;
      const bool valid = eid < e1;
      float pacc = 0.f;
#pragma unroll
      for (int p = 0; p < P; ++p) {
        const f16x2 c2 = f16x2{f[k][2 * p], f[k][2 * p + 1]};
        const f16x2 s = c2 + xr2[p];
        const f16x2 mx = __builtin_elementwise_max(s, f16x2{(_Float16)0.f, (_Float16)0.f});
        const f16x2 mn = __builtin_elementwise_min(s, f16x2{(_Float16)0.f, (_Float16)0.f});
        const f16x2 lk = mn * f16x2{(_Float16)NEG_SLOPE, (_Float16)NEG_SLOPE} + mx;
        pacc = __builtin_amdgcn_fdot2(lk, at2[p], pacc, false);
      }
      // reduce over my 16-lane head row (row-local DPP only, serves 2 edges)
      DPPADD(pacc, 0xB1);
      DPPADD(pacc, 0x4E);
      DPPADD(pacc, 0x124);
      DPPADD(pacc, 0x128);
      if (!valid) pacc = -INFINITY;   // -> w = EXP2(-inf) = 0 below
      if (__any(pacc - m > 11.54f)) {
        const float mn2 = fmaxf(m, pacc);
        const float scale = EXP2(m - mn2);
        const float w = EXP2(pacc - mn2);
        l = l * scale + w;
#pragma unroll
        for (int j = 0; j < V; ++j) O[j] = O[j] * scale + w * (float)f[k][j];
        m = mn2;
      } else {
        const float w = EXP2(pacc - m);
        l += w;
#pragma unroll
        for (int j = 0; j < V; ++j) O[j] += w * (float)f[k][j];
      }
      f[k] = *(const hv*)&feat[(cidx[k] << LOGS) + co];
      const int enn = eid + 4 * D;
      cidx[k] = col[(enn < e1) ? enn : e1m1];
    }
  }

  // merge the two half-wave softmax states (lane L <-> L^32)
  {
    const float m2 = __shfl_xor(m, 32, 64);
    const float l2 = __shfl_xor(l, 32, 64);
    const float mn = fmaxf(m, m2);
    const float s1 = EXP2(m - mn);
    const float s2 = EXP2(m2 - mn);
    l = l * s1 + l2 * s2;
#pragma unroll
    for (int j = 0; j < V; ++j)
      O[j] = O[j] * s1 + __shfl_xor(O[j], 32, 64) * s2;
  }
  if (half) return;                     // lanes 0-31 hold the merged result

  const float inv = 1.f / l;
  if constexpr (OUT16) {
    typedef _Float16 ov __attribute__((ext_vector_type(V)));
    ov o;
#pragma unroll
    for (int j = 0; j < V; ++j) {
      float v = O[j] * inv + bias[co + j];
      if constexpr (RELU) v = fmaxf(v, 0.f);
      o[j] = (_Float16)v;
    }
    *(ov*)&out16[n * (2 * C) + co] = o;
  } else {
#pragma unroll
    for (int q = 0; q < V / 4; ++q) {
      float4 o;
      o.x = O[q * 4 + 0] * inv + bias[co + q * 4 + 0];
      o.y = O[q * 4 + 1] * inv + bias[co + q * 4 + 1];
      o.z = O[q * 4 + 2] * inv + bias[co + q * 4 + 2];
      o.w = O[q * 4 + 3] * inv + bias[co + q * 4 + 3];
      *(float4*)&out32[(size_t)n * (2 * C) + co + q * 4] = o;
    }
  }
}

// ---------------------------------------------------------------------------
extern "C" void kernel_launch(void* const* d_in, const int* in_sizes, int n_in,
                              void* d_out, int out_size, void* d_ws, size_t ws_size,
                              hipStream_t stream) {
  const float* x    = (const float*)d_in[0];
  const int*   ei   = (const int*)d_in[1];
  const float* Wl0  = (const float*)d_in[2];
  const float* Wr0  = (const float*)d_in[3];
  const float* att0 = (const float*)d_in[4];
  const float* b0   = (const float*)d_in[5];
  const float* Wl1  = (const float*)d_in[6];
  const float* Wr1  = (const float*)d_in[7];
  const float* att1 = (const float*)d_in[8];
  const float* b1   = (const float*)d_in[9];
  float* out = (float*)d_out;

  const int N    = in_sizes[0] / 256;
  const int E    = in_sizes[1] / 2;
  const int EA   = E + N;
  const int Mpad = (N + 127) & ~127;   // padded rows for unconditional staging

  _Float16* hw    = (_Float16*)d_ws;
  _Float16* feat0 = hw;                       // N x 256 (overlapped by feat1)
  _Float16* feat1 = hw;                       // N x 512
  _Float16* ha    = hw + (size_t)N * 512;     // Mpad x 128 (L0 out, f16)
  _Float16* xa    = ha + (size_t)Mpad * 128;  // Mpad x 256 (x in f16)
  _Float16* Bt0   = xa + (size_t)Mpad * 256;  // 256 x 256
  _Float16* Bt1   = Bt0 + 65536;              // 512 x 128
  int* rowptr = (int*)(Bt1 + 65536);
  const int cpad = (N + 1 + 3) & ~3;
  int* cnt    = rowptr + cpad;
  int* wo     = cnt + N;
  int* bsum   = wo + N;
  int* col    = bsum + 256;

  const dim3 blk(256);
  const int gEA     = (EA + 255) / 256;
  const int gScan   = (N + 255) / 256;
  const int gM      = Mpad / 128;
  const int gNode   = (N + 3) / 4;
  const int nb_cast = (N * 64 + 255) / 256;

  // 1) zero cnt
  hipMemsetAsync(cnt, 0, (size_t)N * 4, stream);
  // 2) fused setup: cast x, transpose+cast W0/W1, csr_count
  setup_fused<<<nb_cast + 512 + gEA, blk, 0, stream>>>(
      x, xa, Wl0, Wr0, Bt0, Wl1, Wr1, Bt1, ei, E, EA, cnt, nb_cast, N);
  // 3-4) scan chain (scan_block zeroes wo; scan_add self-computes block prefix)
  scan_block<<<gScan, blk, 0, stream>>>(cnt, rowptr, bsum, wo, N);
  scan_add<<<gScan, blk, 0, stream>>>(rowptr, bsum, N, EA);
  // 5) csr_fill (first gEA blocks) overlapped with gemm0 (128x128 tiles)
  gemm_fill<<<gEA + 2 * gM, blk, 0, stream>>>(
      xa, Bt0, feat0, N, 256, 256, ei, E, EA, rowptr, wo, col, gEA);
  // 6) gat0 (C=64, stride 256 halves -> LOGS=8, V=4)
  fused_gat_h2<64, 8, 4, 4, true, true><<<gNode, blk, 0, stream>>>(
      rowptr, col, feat0, att0, b0, ha, nullptr, N);
  // 7) gemm1 (NT=512 -> 4 column tiles)
  hgemm_tn<<<dim3(4, gM), blk, 0, stream>>>(ha, Bt1, feat1, N, 512, 128);
  // 8) gat1 (C=128, stride 512 halves -> LOGS=9, V=8)
  fused_gat_h2<128, 9, 8, 4, false, false><<<gNode, blk, 0, stream>>>(
      rowptr, col, feat1, att1, b1, nullptr, out, N);
}